// Round 1
// baseline (415.565 us; speedup 1.0000x reference)
//
#include <hip/hip_runtime.h>
#include <stdint.h>

#define AS1 __attribute__((address_space(1)))
#define AS3 __attribute__((address_space(3)))

typedef __bf16 bf16x8 __attribute__((ext_vector_type(8)));
typedef float  f32x4  __attribute__((ext_vector_type(4)));

static constexpr int NODES  = 50000;
static constexpr int EDGES  = 800000;
static constexpr int INDIM  = 512;
static constexpr int HIDDIM = 256;
static constexpr int NB_SCAN = (NODES + 255) / 256;   // 196
static constexpr int AGG_BLOCKS = NODES / 4;          // 12500 (exact)
static constexpr int RED_BLOCKS = 64;

// ---------------- ws layout (bytes) ----------------
static constexpr size_t OFF_XB   = 0;            // bf16 [50000][512] (dead after GEMM1)
static constexpr size_t OFF_PART = 0;            // f32  [12500][256] (alias; used after GEMM1)
static constexpr size_t OFF_HN   = 51200000;     // bf16 [50000][256] pre-scaled h (both layers)
static constexpr size_t OFF_H1P  = 76800000;     // bf16 [50000][256] relu(layer1) output
static constexpr size_t OFF_W1T  = 102400000;    // bf16 [256][512]
static constexpr size_t OFF_W2T  = 102662144;    // bf16 [256][256]
static constexpr size_t OFF_DEG  = 102793216;    // i32 [50000]
static constexpr size_t OFF_FILL = 102993216;    // i32 [50000]
static constexpr size_t OFF_ROWP = 103193216;    // i32 [50001]
static constexpr size_t OFF_CSR  = 103393280;    // i32 [800000]
static constexpr size_t OFF_BSUM = 106593280;    // i32 [196]
static constexpr size_t OFF_BOFF = 106594304;    // i32 [256]
static constexpr size_t OFF_FLAG = 106595328;    // i32 (1 => edge_index is int64)
static constexpr size_t OFF_P2   = 106595840;    // f32 [64][256]
static constexpr size_t OFF_DINV = 106661376;    // f32 [50000]

__device__ __forceinline__ unsigned short f2bf(float f) {
  unsigned u = __builtin_bit_cast(unsigned, f);
  unsigned r = (u + 0x7FFFu + ((u >> 16) & 1u)) >> 16;   // RNE
  return (unsigned short)r;
}
__device__ __forceinline__ float bf2f(unsigned short u) {
  return __builtin_bit_cast(float, ((unsigned)u) << 16);
}
__device__ __forceinline__ void gload_lds16(const unsigned short* g, unsigned short* l) {
  __builtin_amdgcn_global_load_lds((const AS1 void*)g, (AS3 void*)l, 16, 0, 0);
}

// ---------------- edge dtype detect ----------------
__global__ void detect_kernel(const int* __restrict__ ei, int* __restrict__ flag) {
  int t = threadIdx.x;  // 64 threads
  unsigned long long b = __ballot(ei[2 * t + 1] == 0);
  if (t == 0) *flag = (b == 0xFFFFFFFFFFFFFFFFull) ? 1 : 0;
}

// ---------------- degree histogram ----------------
__global__ __launch_bounds__(256) void hist_kernel(const int* __restrict__ ei,
                                                   const int* __restrict__ flag,
                                                   int* __restrict__ deg) {
  int e = blockIdx.x * 256 + threadIdx.x;        // grid exact: 3125*256 = 800000
  int f = *flag;
  int d = f ? ei[2 * (EDGES + e)] : ei[EDGES + e];
  atomicAdd(&deg[d], 1);
}

// ---------------- scan (3 kernels) + dinv ----------------
__global__ __launch_bounds__(256) void scan1_kernel(const int* __restrict__ deg,
                                                    int* __restrict__ rowptr,
                                                    int* __restrict__ bsum,
                                                    float* __restrict__ dinv) {
  __shared__ int s[256];
  int t = threadIdx.x, i = blockIdx.x * 256 + t;
  int v = (i < NODES) ? deg[i] : 0;
  if (i < NODES) dinv[i] = rsqrtf((float)(v + 1));   // +1 self-loop
  s[t] = v; __syncthreads();
  for (int off = 1; off < 256; off <<= 1) {
    int x = (t >= off) ? s[t - off] : 0;
    __syncthreads(); s[t] += x; __syncthreads();
  }
  if (i < NODES) rowptr[i] = s[t] - v;               // block-local exclusive
  if (t == 255) bsum[blockIdx.x] = s[255];
}
__global__ __launch_bounds__(256) void scan2_kernel(const int* __restrict__ bsum,
                                                    int* __restrict__ boff,
                                                    int* __restrict__ rowptrN) {
  __shared__ int s[256];
  int t = threadIdx.x;
  int v = (t < NB_SCAN) ? bsum[t] : 0;
  s[t] = v; __syncthreads();
  for (int off = 1; off < 256; off <<= 1) {
    int x = (t >= off) ? s[t - off] : 0;
    __syncthreads(); s[t] += x; __syncthreads();
  }
  if (t < NB_SCAN) boff[t] = s[t] - v;
  if (t == 255) *rowptrN = s[255];
}
__global__ __launch_bounds__(256) void scan3_kernel(int* __restrict__ rowptr,
                                                    const int* __restrict__ boff) {
  int i = blockIdx.x * 256 + threadIdx.x;
  if (i < NODES) rowptr[i] += boff[blockIdx.x];
}

// ---------------- CSR fill ----------------
__global__ __launch_bounds__(256) void fill_kernel(const int* __restrict__ ei,
                                                   const int* __restrict__ flag,
                                                   const int* __restrict__ rowptr,
                                                   int* __restrict__ fill,
                                                   int* __restrict__ csr) {
  int e = blockIdx.x * 256 + threadIdx.x;
  int f = *flag;
  int s, d;
  if (f) { s = ei[2 * e]; d = ei[2 * (EDGES + e)]; }
  else   { s = ei[e];     d = ei[EDGES + e]; }
  int p = atomicAdd(&fill[d], 1);
  csr[rowptr[d] + p] = s;
}

// ---------------- conversions ----------------
__global__ __launch_bounds__(256) void convx_kernel(const float* __restrict__ x,
                                                    unsigned short* __restrict__ xb) {
  size_t i = (size_t)(blockIdx.x * 256 + threadIdx.x) * 8;  // grid exact: 12500*256*8
  float4 v0 = *(const float4*)(x + i);
  float4 v1 = *(const float4*)(x + i + 4);
  ushort4 o0{f2bf(v0.x), f2bf(v0.y), f2bf(v0.z), f2bf(v0.w)};
  ushort4 o1{f2bf(v1.x), f2bf(v1.y), f2bf(v1.z), f2bf(v1.w)};
  *(ushort4*)(xb + i) = o0;
  *(ushort4*)(xb + i + 4) = o1;
}
__global__ __launch_bounds__(256) void transw_kernel(const float* __restrict__ W1,
                                                     const float* __restrict__ W2,
                                                     unsigned short* __restrict__ W1T,
                                                     unsigned short* __restrict__ W2T) {
  int t = blockIdx.x * 256 + threadIdx.x;           // 768*256 = 196608 exact
  if (t < INDIM * HIDDIM) {
    int n = t >> 9, k = t & 511;                    // W1T[n][k] = W1[k][n]
    W1T[t] = f2bf(W1[k * HIDDIM + n]);
  } else {
    int u = t - INDIM * HIDDIM;
    int n = u >> 8, k = u & 255;
    W2T[u] = f2bf(W2[k * HIDDIM + n]);
  }
}

// ---------------- bf16 MFMA GEMM: Cn = (A[M][K] @ BT[256][K]^T) * dinv[row], bf16 out ----
// 128x128 tile, 4 waves (2x2), each wave 64x64 = 4x4 frags of 16x16x32.
__global__ __launch_bounds__(256) void gemm_kernel(const unsigned short* __restrict__ A,
                                                   const unsigned short* __restrict__ BT,
                                                   const float* __restrict__ dinv,
                                                   unsigned short* __restrict__ Cn,
                                                   int M, int K) {
  __shared__ unsigned short As[128 * 32];
  __shared__ unsigned short Bs[128 * 32];
  const int tid = threadIdx.x, wave = tid >> 6, lane = tid & 63;
  const int m0 = blockIdx.y * 128, n0 = blockIdx.x * 128;
  const int wr = wave >> 1, wc = wave & 1;

  f32x4 zero = {0.f, 0.f, 0.f, 0.f};
  f32x4 acc[4][4];
#pragma unroll
  for (int m = 0; m < 4; ++m)
#pragma unroll
    for (int n = 0; n < 4; ++n) acc[m][n] = zero;

  // fragment LDS addresses (constant across k-iterations; tile refilled in place)
  const int fr = lane & 15, kq = (lane >> 4) * 8;
  const bf16x8* aP[4]; const bf16x8* bP[4];
#pragma unroll
  for (int m = 0; m < 4; ++m) aP[m] = (const bf16x8*)&As[(wr * 64 + m * 16 + fr) * 32 + kq];
#pragma unroll
  for (int n = 0; n < 4; ++n) bP[n] = (const bf16x8*)&Bs[(wc * 64 + n * 16 + fr) * 32 + kq];

  const int srow = lane >> 2;          // 0..15 within a 16-row chunk
  const int scol = (lane & 3) * 8;     // element col within BK=32

  for (int k0 = 0; k0 < K; k0 += 32) {
#pragma unroll
    for (int c = 0; c < 2; ++c) {
      int chunk = wave * 2 + c;                     // 0..7, 16 rows each
      int ga = m0 + chunk * 16 + srow; if (ga > M - 1) ga = M - 1;  // clamp M edge
      gload_lds16(A + (size_t)ga * K + k0 + scol, As + chunk * 512);
      int gb = n0 + chunk * 16 + srow;              // always < 256
      gload_lds16(BT + (size_t)gb * K + k0 + scol, Bs + chunk * 512);
    }
    __syncthreads();
    bf16x8 af[4], bq[4];
#pragma unroll
    for (int m = 0; m < 4; ++m) af[m] = *aP[m];
#pragma unroll
    for (int n = 0; n < 4; ++n) bq[n] = *bP[n];
#pragma unroll
    for (int m = 0; m < 4; ++m)
#pragma unroll
      for (int n = 0; n < 4; ++n)
        acc[m][n] = __builtin_amdgcn_mfma_f32_16x16x32_bf16(af[m], bq[n], acc[m][n], 0, 0, 0);
    __syncthreads();
  }

  // epilogue: C/D layout col=lane&15, row=(lane>>4)*4+reg  [m89-verified]
  const int rq = (lane >> 4) * 4;
#pragma unroll
  for (int m = 0; m < 4; ++m) {
    int rbase = m0 + wr * 64 + m * 16 + rq;
#pragma unroll
    for (int r = 0; r < 4; ++r) {
      int grow = rbase + r;
      if (grow < M) {
        float dv = dinv[grow];
#pragma unroll
        for (int n = 0; n < 4; ++n) {
          int gcol = n0 + wc * 64 + n * 16 + fr;
          Cn[(size_t)grow * 256 + gcol] = f2bf(acc[m][n][r] * dv);
        }
      }
    }
  }
}

// ---------------- aggregation: wave per node, CSR gather ----------------
__global__ __launch_bounds__(256) void agg1_kernel(const unsigned short* __restrict__ hn,
                                                   const float* __restrict__ dinv,
                                                   const int* __restrict__ rowptr,
                                                   const int* __restrict__ csr,
                                                   const float* __restrict__ bias,
                                                   unsigned short* __restrict__ outp) {
  int wave = threadIdx.x >> 6, lane = threadIdx.x & 63;
  int node = blockIdx.x * 4 + wave;
  int c0 = lane * 4;
  ushort4 h = *(const ushort4*)(hn + (size_t)node * 256 + c0);   // self-loop term hn[i]
  float a0 = bf2f(h.x), a1 = bf2f(h.y), a2 = bf2f(h.z), a3 = bf2f(h.w);
  int e0 = rowptr[node], e1 = rowptr[node + 1];
  for (int e = e0; e < e1; ++e) {
    int s = csr[e];
    ushort4 v = *(const ushort4*)(hn + (size_t)s * 256 + c0);
    a0 += bf2f(v.x); a1 += bf2f(v.y); a2 += bf2f(v.z); a3 += bf2f(v.w);
  }
  float di = dinv[node];
  float4 b = *(const float4*)(bias + c0);
  ushort4 o{f2bf(fmaxf(fmaf(di, a0, b.x), 0.f)),
            f2bf(fmaxf(fmaf(di, a1, b.y), 0.f)),
            f2bf(fmaxf(fmaf(di, a2, b.z), 0.f)),
            f2bf(fmaxf(fmaf(di, a3, b.w), 0.f))};
  *(ushort4*)(outp + (size_t)node * 256 + c0) = o;
}

__global__ __launch_bounds__(256) void agg2_kernel(const unsigned short* __restrict__ hn,
                                                   const float* __restrict__ dinv,
                                                   const int* __restrict__ rowptr,
                                                   const int* __restrict__ csr,
                                                   const float* __restrict__ bias,
                                                   float* __restrict__ partials) {
  __shared__ float sm[1024];
  int wave = threadIdx.x >> 6, lane = threadIdx.x & 63;
  int node = blockIdx.x * 4 + wave;                 // 12500*4 = 50000 exact
  int c0 = lane * 4;
  ushort4 h = *(const ushort4*)(hn + (size_t)node * 256 + c0);
  float a0 = bf2f(h.x), a1 = bf2f(h.y), a2 = bf2f(h.z), a3 = bf2f(h.w);
  int e0 = rowptr[node], e1 = rowptr[node + 1];
  for (int e = e0; e < e1; ++e) {
    int s = csr[e];
    ushort4 v = *(const ushort4*)(hn + (size_t)s * 256 + c0);
    a0 += bf2f(v.x); a1 += bf2f(v.y); a2 += bf2f(v.z); a3 += bf2f(v.w);
  }
  float di = dinv[node];
  float4 b = *(const float4*)(bias + c0);
  sm[wave * 256 + c0 + 0] = fmaxf(fmaf(di, a0, b.x), 0.f);
  sm[wave * 256 + c0 + 1] = fmaxf(fmaf(di, a1, b.y), 0.f);
  sm[wave * 256 + c0 + 2] = fmaxf(fmaf(di, a2, b.z), 0.f);
  sm[wave * 256 + c0 + 3] = fmaxf(fmaf(di, a3, b.w), 0.f);
  __syncthreads();
  int t = threadIdx.x;
  partials[(size_t)blockIdx.x * 256 + t] = sm[t] + sm[256 + t] + sm[512 + t] + sm[768 + t];
}

// ---------------- readout ----------------
__global__ __launch_bounds__(256) void reduce2_kernel(const float* __restrict__ partials,
                                                      float* __restrict__ p2) {
  int t = threadIdx.x, b = blockIdx.x;              // 64 blocks
  float s = 0.f;
  for (int r = b; r < AGG_BLOCKS; r += RED_BLOCKS) s += partials[(size_t)r * 256 + t];
  p2[b * 256 + t] = s;
}
__global__ __launch_bounds__(256) void final_kernel(const float* __restrict__ p2,
                                                    const float* __restrict__ Wfc,
                                                    const float* __restrict__ bfc,
                                                    float* __restrict__ out) {
  __shared__ float red[256];
  int t = threadIdx.x;
  float s = 0.f;
  for (int b = 0; b < RED_BLOCKS; ++b) s += p2[b * 256 + t];
  float g = s * (1.0f / (float)NODES);
  red[t] = g * Wfc[t];
  __syncthreads();
  for (int off = 128; off > 0; off >>= 1) {
    if (t < off) red[t] += red[t + off];
    __syncthreads();
  }
  if (t == 0) {
    float z = red[0] + bfc[0];
    out[0] = 1.0f / (1.0f + expf(-z));
  }
}

// ---------------- launch ----------------
extern "C" void kernel_launch(void* const* d_in, const int* in_sizes, int n_in,
                              void* d_out, int out_size, void* d_ws, size_t ws_size,
                              hipStream_t stream) {
  (void)in_sizes; (void)n_in; (void)out_size; (void)ws_size;
  const float* x   = (const float*)d_in[0];
  const int*   ei  = (const int*)d_in[1];
  const float* W1  = (const float*)d_in[2];
  const float* b1  = (const float*)d_in[3];
  const float* W2  = (const float*)d_in[4];
  const float* b2  = (const float*)d_in[5];
  const float* Wfc = (const float*)d_in[6];
  const float* bfc = (const float*)d_in[7];
  float* out = (float*)d_out;
  char* ws = (char*)d_ws;

  unsigned short* xb   = (unsigned short*)(ws + OFF_XB);
  unsigned short* hn   = (unsigned short*)(ws + OFF_HN);
  unsigned short* h1p  = (unsigned short*)(ws + OFF_H1P);
  unsigned short* w1t  = (unsigned short*)(ws + OFF_W1T);
  unsigned short* w2t  = (unsigned short*)(ws + OFF_W2T);
  int*   deg    = (int*)(ws + OFF_DEG);
  int*   fill   = (int*)(ws + OFF_FILL);
  int*   rowptr = (int*)(ws + OFF_ROWP);
  int*   csr    = (int*)(ws + OFF_CSR);
  int*   bsum   = (int*)(ws + OFF_BSUM);
  int*   boff   = (int*)(ws + OFF_BOFF);
  int*   flag   = (int*)(ws + OFF_FLAG);
  float* part   = (float*)(ws + OFF_PART);
  float* p2     = (float*)(ws + OFF_P2);
  float* dinv   = (float*)(ws + OFF_DINV);

  // zero deg + fill (contiguous 400000 B)
  hipMemsetAsync(ws + OFF_DEG, 0, 400000, stream);
  detect_kernel<<<1, 64, 0, stream>>>(ei, flag);
  hist_kernel<<<EDGES / 256, 256, 0, stream>>>(ei, flag, deg);
  scan1_kernel<<<NB_SCAN, 256, 0, stream>>>(deg, rowptr, bsum, dinv);
  scan2_kernel<<<1, 256, 0, stream>>>(bsum, boff, rowptr + NODES);
  scan3_kernel<<<NB_SCAN, 256, 0, stream>>>(rowptr, boff);
  fill_kernel<<<EDGES / 256, 256, 0, stream>>>(ei, flag, rowptr, fill, csr);

  convx_kernel<<<NODES * INDIM / (256 * 8), 256, 0, stream>>>(x, xb);
  transw_kernel<<<(INDIM * HIDDIM + HIDDIM * HIDDIM) / 256, 256, 0, stream>>>(W1, W2, w1t, w2t);

  dim3 ggrid(HIDDIM / 128, (NODES + 127) / 128);    // (2, 391)
  gemm_kernel<<<ggrid, 256, 0, stream>>>(xb, w1t, dinv, hn, NODES, INDIM);
  agg1_kernel<<<AGG_BLOCKS, 256, 0, stream>>>(hn, dinv, rowptr, csr, b1, h1p);
  gemm_kernel<<<ggrid, 256, 0, stream>>>(h1p, w2t, dinv, hn, NODES, HIDDIM);
  agg2_kernel<<<AGG_BLOCKS, 256, 0, stream>>>(hn, dinv, rowptr, csr, b2, part);
  reduce2_kernel<<<RED_BLOCKS, 256, 0, stream>>>(part, p2);
  final_kernel<<<1, 256, 0, stream>>>(p2, Wfc, bfc, out);
}

// Round 2
// 340.966 us; speedup vs baseline: 1.2188x; 1.2188x over previous
//
#include <hip/hip_runtime.h>
#include <stdint.h>

#define AS1 __attribute__((address_space(1)))
#define AS3 __attribute__((address_space(3)))

typedef __bf16 bf16x8 __attribute__((ext_vector_type(8)));
typedef float  f32x4  __attribute__((ext_vector_type(4)));

static constexpr int NODES  = 50000;
static constexpr int EDGES  = 800000;
static constexpr int INDIM  = 512;
static constexpr int HIDDIM = 256;
static constexpr int NB_SCAN = (NODES + 255) / 256;   // 196
static constexpr int AGG_BLOCKS = NODES / 4;          // 12500 (exact)
static constexpr int RED_BLOCKS = 64;

// ---------------- ws layout (bytes) ----------------
static constexpr size_t OFF_PART = 0;            // f32  [12500][256]
static constexpr size_t OFF_HN   = 51200000;     // bf16 [50000][256] pre-scaled h (both layers)
static constexpr size_t OFF_H1P  = 76800000;     // bf16 [50000][256] relu(layer1) output
static constexpr size_t OFF_W1T  = 102400000;    // bf16 [256][512]
static constexpr size_t OFF_W2T  = 102662144;    // bf16 [256][256]
static constexpr size_t OFF_DEG  = 102793216;    // i32 [50000]
static constexpr size_t OFF_FILL = 102993216;    // i32 [50000]
static constexpr size_t OFF_ROWP = 103193216;    // i32 [50001]
static constexpr size_t OFF_CSR  = 103393280;    // i32 [800000]
static constexpr size_t OFF_BSUM = 106593280;    // i32 [196]
static constexpr size_t OFF_BOFF = 106594304;    // i32 [256]
static constexpr size_t OFF_FLAG = 106595328;    // i32 (1 => edge_index is int64)
static constexpr size_t OFF_P2   = 106595840;    // f32 [64][256]
static constexpr size_t OFF_DINV = 106661376;    // f32 [50000]

__device__ __forceinline__ unsigned short f2bf(float f) {
  unsigned u = __builtin_bit_cast(unsigned, f);
  unsigned r = (u + 0x7FFFu + ((u >> 16) & 1u)) >> 16;   // RNE
  return (unsigned short)r;
}
__device__ __forceinline__ float bf2f(unsigned short u) {
  return __builtin_bit_cast(float, ((unsigned)u) << 16);
}
__device__ __forceinline__ void gload_lds16(const unsigned short* g, unsigned short* l) {
  __builtin_amdgcn_global_load_lds((const AS1 void*)g, (AS3 void*)l, 16, 0, 0);
}

// ---------------- edge dtype detect ----------------
__global__ void detect_kernel(const int* __restrict__ ei, int* __restrict__ flag) {
  int t = threadIdx.x;  // 64 threads
  unsigned long long b = __ballot(ei[2 * t + 1] == 0);
  if (t == 0) *flag = (b == 0xFFFFFFFFFFFFFFFFull) ? 1 : 0;
}

// ---------------- degree histogram ----------------
__global__ __launch_bounds__(256) void hist_kernel(const int* __restrict__ ei,
                                                   const int* __restrict__ flag,
                                                   int* __restrict__ deg) {
  int e = blockIdx.x * 256 + threadIdx.x;        // grid exact: 3125*256 = 800000
  int f = *flag;
  int d = f ? ei[2 * (EDGES + e)] : ei[EDGES + e];
  atomicAdd(&deg[d], 1);
}

// ---------------- scan (3 kernels) + dinv ----------------
__global__ __launch_bounds__(256) void scan1_kernel(const int* __restrict__ deg,
                                                    int* __restrict__ rowptr,
                                                    int* __restrict__ bsum,
                                                    float* __restrict__ dinv) {
  __shared__ int s[256];
  int t = threadIdx.x, i = blockIdx.x * 256 + t;
  int v = (i < NODES) ? deg[i] : 0;
  if (i < NODES) dinv[i] = rsqrtf((float)(v + 1));   // +1 self-loop
  s[t] = v; __syncthreads();
  for (int off = 1; off < 256; off <<= 1) {
    int x = (t >= off) ? s[t - off] : 0;
    __syncthreads(); s[t] += x; __syncthreads();
  }
  if (i < NODES) rowptr[i] = s[t] - v;               // block-local exclusive
  if (t == 255) bsum[blockIdx.x] = s[255];
}
__global__ __launch_bounds__(256) void scan2_kernel(const int* __restrict__ bsum,
                                                    int* __restrict__ boff,
                                                    int* __restrict__ rowptrN) {
  __shared__ int s[256];
  int t = threadIdx.x;
  int v = (t < NB_SCAN) ? bsum[t] : 0;
  s[t] = v; __syncthreads();
  for (int off = 1; off < 256; off <<= 1) {
    int x = (t >= off) ? s[t - off] : 0;
    __syncthreads(); s[t] += x; __syncthreads();
  }
  if (t < NB_SCAN) boff[t] = s[t] - v;
  if (t == 255) *rowptrN = s[255];
}
__global__ __launch_bounds__(256) void scan3_kernel(int* __restrict__ rowptr,
                                                    const int* __restrict__ boff) {
  int i = blockIdx.x * 256 + threadIdx.x;
  if (i < NODES) rowptr[i] += boff[blockIdx.x];
}

// ---------------- CSR fill ----------------
__global__ __launch_bounds__(256) void fill_kernel(const int* __restrict__ ei,
                                                   const int* __restrict__ flag,
                                                   const int* __restrict__ rowptr,
                                                   int* __restrict__ fill,
                                                   int* __restrict__ csr) {
  int e = blockIdx.x * 256 + threadIdx.x;
  int f = *flag;
  int s, d;
  if (f) { s = ei[2 * e]; d = ei[2 * (EDGES + e)]; }
  else   { s = ei[e];     d = ei[EDGES + e]; }
  int p = atomicAdd(&fill[d], 1);
  csr[rowptr[d] + p] = s;
}

// ---------------- weight transpose + bf16 ----------------
__global__ __launch_bounds__(256) void transw_kernel(const float* __restrict__ W1,
                                                     const float* __restrict__ W2,
                                                     unsigned short* __restrict__ W1T,
                                                     unsigned short* __restrict__ W2T) {
  int t = blockIdx.x * 256 + threadIdx.x;           // 768*256 = 196608 exact
  if (t < INDIM * HIDDIM) {
    int n = t >> 9, k = t & 511;                    // W1T[n][k] = W1[k][n]
    W1T[t] = f2bf(W1[k * HIDDIM + n]);
  } else {
    int u = t - INDIM * HIDDIM;
    int n = u >> 8, k = u & 255;
    W2T[u] = f2bf(W2[k * HIDDIM + n]);
  }
}

// ---------------- GEMM1: fp32 A (x) fused-convert, bf16 B; Cn = (x@W1)*dinv, bf16 ----
// 128x128 tile, 4 waves (2x2), each wave 64x64 = 4x4 frags of 16x16x32. K=512.
__global__ __launch_bounds__(256) void gemm1_kernel(const float* __restrict__ A,
                                                    const unsigned short* __restrict__ BT,
                                                    const float* __restrict__ dinv,
                                                    unsigned short* __restrict__ Cn) {
  const int M = NODES, K = INDIM;
  __shared__ unsigned short As[128 * 32];
  __shared__ unsigned short Bs[128 * 32];
  const int tid = threadIdx.x, wave = tid >> 6, lane = tid & 63;
  const int m0 = blockIdx.y * 128, n0 = blockIdx.x * 128;
  const int wr = wave >> 1, wc = wave & 1;

  f32x4 zero = {0.f, 0.f, 0.f, 0.f};
  f32x4 acc[4][4];
#pragma unroll
  for (int m = 0; m < 4; ++m)
#pragma unroll
    for (int n = 0; n < 4; ++n) acc[m][n] = zero;

  const int fr = lane & 15, kq = (lane >> 4) * 8;
  const bf16x8* aP[4]; const bf16x8* bP[4];
#pragma unroll
  for (int m = 0; m < 4; ++m) aP[m] = (const bf16x8*)&As[(wr * 64 + m * 16 + fr) * 32 + kq];
#pragma unroll
  for (int n = 0; n < 4; ++n) bP[n] = (const bf16x8*)&Bs[(wc * 64 + n * 16 + fr) * 32 + kq];

  const int srow = lane >> 2, scol = (lane & 3) * 8;

  for (int k0 = 0; k0 < K; k0 += 32) {
    // A: fp32 -> bf16 reg-staged. 128x32 tile, 4 passes x 256 thr x float4.
#pragma unroll
    for (int p = 0; p < 4; ++p) {
      int f = (p * 256 + tid) * 4;                  // flat elem idx in 128x32 tile
      int row = f >> 5, col = f & 31;
      int ga = m0 + row; if (ga > M - 1) ga = M - 1;
      float4 v = *(const float4*)(A + (size_t)ga * K + k0 + col);
      ushort4 o{f2bf(v.x), f2bf(v.y), f2bf(v.z), f2bf(v.w)};
      *(ushort4*)(As + f) = o;
    }
    // B: direct global->LDS
#pragma unroll
    for (int c = 0; c < 2; ++c) {
      int chunk = wave * 2 + c;
      int gb = n0 + chunk * 16 + srow;
      gload_lds16(BT + (size_t)gb * K + k0 + scol, Bs + chunk * 512);
    }
    __syncthreads();
    bf16x8 af[4], bq[4];
#pragma unroll
    for (int m = 0; m < 4; ++m) af[m] = *aP[m];
#pragma unroll
    for (int n = 0; n < 4; ++n) bq[n] = *bP[n];
#pragma unroll
    for (int m = 0; m < 4; ++m)
#pragma unroll
      for (int n = 0; n < 4; ++n)
        acc[m][n] = __builtin_amdgcn_mfma_f32_16x16x32_bf16(af[m], bq[n], acc[m][n], 0, 0, 0);
    __syncthreads();
  }

  const int rq = (lane >> 4) * 4;
#pragma unroll
  for (int m = 0; m < 4; ++m) {
    int rbase = m0 + wr * 64 + m * 16 + rq;
#pragma unroll
    for (int r = 0; r < 4; ++r) {
      int grow = rbase + r;
      if (grow < M) {
        float dv = dinv[grow];
#pragma unroll
        for (int n = 0; n < 4; ++n) {
          int gcol = n0 + wc * 64 + n * 16 + fr;
          Cn[(size_t)grow * 256 + gcol] = f2bf(acc[m][n][r] * dv);
        }
      }
    }
  }
}

// ---------------- GEMM2: bf16 A, bf16 B; Cn = (A@W2)*dinv, bf16 out ----
__global__ __launch_bounds__(256) void gemm_kernel(const unsigned short* __restrict__ A,
                                                   const unsigned short* __restrict__ BT,
                                                   const float* __restrict__ dinv,
                                                   unsigned short* __restrict__ Cn,
                                                   int M, int K) {
  __shared__ unsigned short As[128 * 32];
  __shared__ unsigned short Bs[128 * 32];
  const int tid = threadIdx.x, wave = tid >> 6, lane = tid & 63;
  const int m0 = blockIdx.y * 128, n0 = blockIdx.x * 128;
  const int wr = wave >> 1, wc = wave & 1;

  f32x4 zero = {0.f, 0.f, 0.f, 0.f};
  f32x4 acc[4][4];
#pragma unroll
  for (int m = 0; m < 4; ++m)
#pragma unroll
    for (int n = 0; n < 4; ++n) acc[m][n] = zero;

  const int fr = lane & 15, kq = (lane >> 4) * 8;
  const bf16x8* aP[4]; const bf16x8* bP[4];
#pragma unroll
  for (int m = 0; m < 4; ++m) aP[m] = (const bf16x8*)&As[(wr * 64 + m * 16 + fr) * 32 + kq];
#pragma unroll
  for (int n = 0; n < 4; ++n) bP[n] = (const bf16x8*)&Bs[(wc * 64 + n * 16 + fr) * 32 + kq];

  const int srow = lane >> 2, scol = (lane & 3) * 8;

  for (int k0 = 0; k0 < K; k0 += 32) {
#pragma unroll
    for (int c = 0; c < 2; ++c) {
      int chunk = wave * 2 + c;
      int ga = m0 + chunk * 16 + srow; if (ga > M - 1) ga = M - 1;
      gload_lds16(A + (size_t)ga * K + k0 + scol, As + chunk * 512);
      int gb = n0 + chunk * 16 + srow;
      gload_lds16(BT + (size_t)gb * K + k0 + scol, Bs + chunk * 512);
    }
    __syncthreads();
    bf16x8 af[4], bq[4];
#pragma unroll
    for (int m = 0; m < 4; ++m) af[m] = *aP[m];
#pragma unroll
    for (int n = 0; n < 4; ++n) bq[n] = *bP[n];
#pragma unroll
    for (int m = 0; m < 4; ++m)
#pragma unroll
      for (int n = 0; n < 4; ++n)
        acc[m][n] = __builtin_amdgcn_mfma_f32_16x16x32_bf16(af[m], bq[n], acc[m][n], 0, 0, 0);
    __syncthreads();
  }

  const int rq = (lane >> 4) * 4;
#pragma unroll
  for (int m = 0; m < 4; ++m) {
    int rbase = m0 + wr * 64 + m * 16 + rq;
#pragma unroll
    for (int r = 0; r < 4; ++r) {
      int grow = rbase + r;
      if (grow < M) {
        float dv = dinv[grow];
#pragma unroll
        for (int n = 0; n < 4; ++n) {
          int gcol = n0 + wc * 64 + n * 16 + fr;
          Cn[(size_t)grow * 256 + gcol] = f2bf(acc[m][n][r] * dv);
        }
      }
    }
  }
}

// ---------------- gather core: unroll-4 edge loop, 4 rows in flight ----------------
__device__ __forceinline__ float4 gather_node(const unsigned short* __restrict__ hn,
                                              const int* __restrict__ rowptr,
                                              const int* __restrict__ csr,
                                              int node, int c0) {
  ushort4 h = *(const ushort4*)(hn + (size_t)node * 256 + c0);   // self-loop term
  float a0 = bf2f(h.x), a1 = bf2f(h.y), a2 = bf2f(h.z), a3 = bf2f(h.w);
  float b0 = 0.f, b1 = 0.f, b2 = 0.f, b3 = 0.f;
  int e0 = rowptr[node], e1 = rowptr[node + 1];
  int e = e0;
  for (; e + 4 <= e1; e += 4) {
    int s0 = csr[e], s1 = csr[e + 1], s2 = csr[e + 2], s3 = csr[e + 3];
    ushort4 v0 = *(const ushort4*)(hn + (size_t)s0 * 256 + c0);
    ushort4 v1 = *(const ushort4*)(hn + (size_t)s1 * 256 + c0);
    ushort4 v2 = *(const ushort4*)(hn + (size_t)s2 * 256 + c0);
    ushort4 v3 = *(const ushort4*)(hn + (size_t)s3 * 256 + c0);
    a0 += bf2f(v0.x) + bf2f(v1.x);  b0 += bf2f(v2.x) + bf2f(v3.x);
    a1 += bf2f(v0.y) + bf2f(v1.y);  b1 += bf2f(v2.y) + bf2f(v3.y);
    a2 += bf2f(v0.z) + bf2f(v1.z);  b2 += bf2f(v2.z) + bf2f(v3.z);
    a3 += bf2f(v0.w) + bf2f(v1.w);  b3 += bf2f(v2.w) + bf2f(v3.w);
  }
  for (; e < e1; ++e) {
    int s = csr[e];
    ushort4 v = *(const ushort4*)(hn + (size_t)s * 256 + c0);
    a0 += bf2f(v.x); a1 += bf2f(v.y); a2 += bf2f(v.z); a3 += bf2f(v.w);
  }
  return float4{a0 + b0, a1 + b1, a2 + b2, a3 + b3};
}

// ---------------- aggregation: wave per node, CSR gather ----------------
__global__ __launch_bounds__(256) void agg1_kernel(const unsigned short* __restrict__ hn,
                                                   const float* __restrict__ dinv,
                                                   const int* __restrict__ rowptr,
                                                   const int* __restrict__ csr,
                                                   const float* __restrict__ bias,
                                                   unsigned short* __restrict__ outp) {
  int wave = threadIdx.x >> 6, lane = threadIdx.x & 63;
  int node = blockIdx.x * 4 + wave;
  int c0 = lane * 4;
  float4 a = gather_node(hn, rowptr, csr, node, c0);
  float di = dinv[node];
  float4 b = *(const float4*)(bias + c0);
  ushort4 o{f2bf(fmaxf(fmaf(di, a.x, b.x), 0.f)),
            f2bf(fmaxf(fmaf(di, a.y, b.y), 0.f)),
            f2bf(fmaxf(fmaf(di, a.z, b.z), 0.f)),
            f2bf(fmaxf(fmaf(di, a.w, b.w), 0.f))};
  *(ushort4*)(outp + (size_t)node * 256 + c0) = o;
}

__global__ __launch_bounds__(256) void agg2_kernel(const unsigned short* __restrict__ hn,
                                                   const float* __restrict__ dinv,
                                                   const int* __restrict__ rowptr,
                                                   const int* __restrict__ csr,
                                                   const float* __restrict__ bias,
                                                   float* __restrict__ partials) {
  __shared__ float sm[1024];
  int wave = threadIdx.x >> 6, lane = threadIdx.x & 63;
  int node = blockIdx.x * 4 + wave;                 // 12500*4 = 50000 exact
  int c0 = lane * 4;
  float4 a = gather_node(hn, rowptr, csr, node, c0);
  float di = dinv[node];
  float4 b = *(const float4*)(bias + c0);
  sm[wave * 256 + c0 + 0] = fmaxf(fmaf(di, a.x, b.x), 0.f);
  sm[wave * 256 + c0 + 1] = fmaxf(fmaf(di, a.y, b.y), 0.f);
  sm[wave * 256 + c0 + 2] = fmaxf(fmaf(di, a.z, b.z), 0.f);
  sm[wave * 256 + c0 + 3] = fmaxf(fmaf(di, a.w, b.w), 0.f);
  __syncthreads();
  int t = threadIdx.x;
  partials[(size_t)blockIdx.x * 256 + t] = sm[t] + sm[256 + t] + sm[512 + t] + sm[768 + t];
}

// ---------------- readout ----------------
__global__ __launch_bounds__(256) void reduce2_kernel(const float* __restrict__ partials,
                                                      float* __restrict__ p2) {
  int t = threadIdx.x, b = blockIdx.x;              // 64 blocks
  float s = 0.f;
  for (int r = b; r < AGG_BLOCKS; r += RED_BLOCKS) s += partials[(size_t)r * 256 + t];
  p2[b * 256 + t] = s;
}
__global__ __launch_bounds__(256) void final_kernel(const float* __restrict__ p2,
                                                    const float* __restrict__ Wfc,
                                                    const float* __restrict__ bfc,
                                                    float* __restrict__ out) {
  __shared__ float red[256];
  int t = threadIdx.x;
  float s = 0.f;
  for (int b = 0; b < RED_BLOCKS; ++b) s += p2[b * 256 + t];
  float g = s * (1.0f / (float)NODES);
  red[t] = g * Wfc[t];
  __syncthreads();
  for (int off = 128; off > 0; off >>= 1) {
    if (t < off) red[t] += red[t + off];
    __syncthreads();
  }
  if (t == 0) {
    float z = red[0] + bfc[0];
    out[0] = 1.0f / (1.0f + expf(-z));
  }
}

// ---------------- launch ----------------
extern "C" void kernel_launch(void* const* d_in, const int* in_sizes, int n_in,
                              void* d_out, int out_size, void* d_ws, size_t ws_size,
                              hipStream_t stream) {
  (void)in_sizes; (void)n_in; (void)out_size; (void)ws_size;
  const float* x   = (const float*)d_in[0];
  const int*   ei  = (const int*)d_in[1];
  const float* W1  = (const float*)d_in[2];
  const float* b1  = (const float*)d_in[3];
  const float* W2  = (const float*)d_in[4];
  const float* b2  = (const float*)d_in[5];
  const float* Wfc = (const float*)d_in[6];
  const float* bfc = (const float*)d_in[7];
  float* out = (float*)d_out;
  char* ws = (char*)d_ws;

  unsigned short* hn   = (unsigned short*)(ws + OFF_HN);
  unsigned short* h1p  = (unsigned short*)(ws + OFF_H1P);
  unsigned short* w1t  = (unsigned short*)(ws + OFF_W1T);
  unsigned short* w2t  = (unsigned short*)(ws + OFF_W2T);
  int*   deg    = (int*)(ws + OFF_DEG);
  int*   fill   = (int*)(ws + OFF_FILL);
  int*   rowptr = (int*)(ws + OFF_ROWP);
  int*   csr    = (int*)(ws + OFF_CSR);
  int*   bsum   = (int*)(ws + OFF_BSUM);
  int*   boff   = (int*)(ws + OFF_BOFF);
  int*   flag   = (int*)(ws + OFF_FLAG);
  float* part   = (float*)(ws + OFF_PART);
  float* p2     = (float*)(ws + OFF_P2);
  float* dinv   = (float*)(ws + OFF_DINV);

  hipMemsetAsync(ws + OFF_DEG, 0, 400000, stream);  // deg + fill
  detect_kernel<<<1, 64, 0, stream>>>(ei, flag);
  hist_kernel<<<EDGES / 256, 256, 0, stream>>>(ei, flag, deg);
  scan1_kernel<<<NB_SCAN, 256, 0, stream>>>(deg, rowptr, bsum, dinv);
  scan2_kernel<<<1, 256, 0, stream>>>(bsum, boff, rowptr + NODES);
  scan3_kernel<<<NB_SCAN, 256, 0, stream>>>(rowptr, boff);
  fill_kernel<<<EDGES / 256, 256, 0, stream>>>(ei, flag, rowptr, fill, csr);

  transw_kernel<<<(INDIM * HIDDIM + HIDDIM * HIDDIM) / 256, 256, 0, stream>>>(W1, W2, w1t, w2t);

  dim3 ggrid(HIDDIM / 128, (NODES + 127) / 128);    // (2, 391)
  gemm1_kernel<<<ggrid, 256, 0, stream>>>(x, w1t, dinv, hn);
  agg1_kernel<<<AGG_BLOCKS, 256, 0, stream>>>(hn, dinv, rowptr, csr, b1, h1p);
  gemm_kernel<<<ggrid, 256, 0, stream>>>(h1p, w2t, dinv, hn, NODES, HIDDIM);
  agg2_kernel<<<AGG_BLOCKS, 256, 0, stream>>>(hn, dinv, rowptr, csr, b2, part);
  reduce2_kernel<<<RED_BLOCKS, 256, 0, stream>>>(part, p2);
  final_kernel<<<1, 256, 0, stream>>>(p2, Wfc, bfc, out);
}

// Round 3
// 325.180 us; speedup vs baseline: 1.2780x; 1.0485x over previous
//
#include <hip/hip_runtime.h>
#include <stdint.h>

#define AS1 __attribute__((address_space(1)))
#define AS3 __attribute__((address_space(3)))

typedef __bf16 bf16x8 __attribute__((ext_vector_type(8)));
typedef float  f32x4  __attribute__((ext_vector_type(4)));

static constexpr int NODES  = 50000;
static constexpr int EDGES  = 800000;
static constexpr int INDIM  = 512;
static constexpr int HIDDIM = 256;
static constexpr int NB_SCAN = (NODES + 255) / 256;   // 196
static constexpr int AGG_BLOCKS = NODES / 4;          // 12500 (exact)
static constexpr int RED_BLOCKS = 64;
static constexpr int GEMM_MB = (NODES + 63) / 64;     // 782 row-blocks (BM=64)

// ---------------- ws layout (bytes) ----------------
static constexpr size_t OFF_PART = 0;            // f32  [12500][256]
static constexpr size_t OFF_HN   = 51200000;     // bf16 [50000][256] pre-scaled h (both layers)
static constexpr size_t OFF_H1P  = 76800000;     // bf16 [50000][256] relu(layer1) output
static constexpr size_t OFF_W1T  = 102400000;    // bf16 [256][512]
static constexpr size_t OFF_W2T  = 102662144;    // bf16 [256][256]
static constexpr size_t OFF_DEG  = 102793216;    // i32 [50000]
static constexpr size_t OFF_FILL = 102993216;    // i32 [50000]
static constexpr size_t OFF_ROWP = 103193216;    // i32 [50001]
static constexpr size_t OFF_CSR  = 103393280;    // i32 [800000]
static constexpr size_t OFF_BSUM = 106593280;    // i32 [196]
static constexpr size_t OFF_BOFF = 106594304;    // i32 [256]
static constexpr size_t OFF_FLAG = 106595328;    // i32 (1 => edge_index is int64)
static constexpr size_t OFF_P2   = 106595840;    // f32 [64][256]
static constexpr size_t OFF_DINV = 106661376;    // f32 [50000]

__device__ __forceinline__ unsigned short f2bf(float f) {
  unsigned u = __builtin_bit_cast(unsigned, f);
  unsigned r = (u + 0x7FFFu + ((u >> 16) & 1u)) >> 16;   // RNE
  return (unsigned short)r;
}
__device__ __forceinline__ float bf2f(unsigned short u) {
  return __builtin_bit_cast(float, ((unsigned)u) << 16);
}
__device__ __forceinline__ ushort4 cvt4(float4 v) {
  return ushort4{f2bf(v.x), f2bf(v.y), f2bf(v.z), f2bf(v.w)};
}
__device__ __forceinline__ void gload_lds16(const unsigned short* g, unsigned short* l) {
  __builtin_amdgcn_global_load_lds((const AS1 void*)g, (AS3 void*)l, 16, 0, 0);
}

// ---------------- edge dtype detect ----------------
__global__ void detect_kernel(const int* __restrict__ ei, int* __restrict__ flag) {
  int t = threadIdx.x;  // 64 threads
  unsigned long long b = __ballot(ei[2 * t + 1] == 0);
  if (t == 0) *flag = (b == 0xFFFFFFFFFFFFFFFFull) ? 1 : 0;
}

// ---------------- degree histogram ----------------
__global__ __launch_bounds__(256) void hist_kernel(const int* __restrict__ ei,
                                                   const int* __restrict__ flag,
                                                   int* __restrict__ deg) {
  int e = blockIdx.x * 256 + threadIdx.x;        // grid exact: 3125*256 = 800000
  int f = *flag;
  int d = f ? ei[2 * (EDGES + e)] : ei[EDGES + e];
  atomicAdd(&deg[d], 1);
}

// ---------------- scan (3 kernels) + dinv ----------------
__global__ __launch_bounds__(256) void scan1_kernel(const int* __restrict__ deg,
                                                    int* __restrict__ rowptr,
                                                    int* __restrict__ bsum,
                                                    float* __restrict__ dinv) {
  __shared__ int s[256];
  int t = threadIdx.x, i = blockIdx.x * 256 + t;
  int v = (i < NODES) ? deg[i] : 0;
  if (i < NODES) dinv[i] = rsqrtf((float)(v + 1));   // +1 self-loop
  s[t] = v; __syncthreads();
  for (int off = 1; off < 256; off <<= 1) {
    int x = (t >= off) ? s[t - off] : 0;
    __syncthreads(); s[t] += x; __syncthreads();
  }
  if (i < NODES) rowptr[i] = s[t] - v;               // block-local exclusive
  if (t == 255) bsum[blockIdx.x] = s[255];
}
__global__ __launch_bounds__(256) void scan2_kernel(const int* __restrict__ bsum,
                                                    int* __restrict__ boff,
                                                    int* __restrict__ rowptrN) {
  __shared__ int s[256];
  int t = threadIdx.x;
  int v = (t < NB_SCAN) ? bsum[t] : 0;
  s[t] = v; __syncthreads();
  for (int off = 1; off < 256; off <<= 1) {
    int x = (t >= off) ? s[t - off] : 0;
    __syncthreads(); s[t] += x; __syncthreads();
  }
  if (t < NB_SCAN) boff[t] = s[t] - v;
  if (t == 255) *rowptrN = s[255];
}
__global__ __launch_bounds__(256) void scan3_kernel(int* __restrict__ rowptr,
                                                    const int* __restrict__ boff) {
  int i = blockIdx.x * 256 + threadIdx.x;
  if (i < NODES) rowptr[i] += boff[blockIdx.x];
}

// ---------------- CSR fill ----------------
__global__ __launch_bounds__(256) void fill_kernel(const int* __restrict__ ei,
                                                   const int* __restrict__ flag,
                                                   const int* __restrict__ rowptr,
                                                   int* __restrict__ fill,
                                                   int* __restrict__ csr) {
  int e = blockIdx.x * 256 + threadIdx.x;
  int f = *flag;
  int s, d;
  if (f) { s = ei[2 * e]; d = ei[2 * (EDGES + e)]; }
  else   { s = ei[e];     d = ei[EDGES + e]; }
  int p = atomicAdd(&fill[d], 1);
  csr[rowptr[d] + p] = s;
}

// ---------------- weight transpose + bf16 ----------------
__global__ __launch_bounds__(256) void transw_kernel(const float* __restrict__ W1,
                                                     const float* __restrict__ W2,
                                                     unsigned short* __restrict__ W1T,
                                                     unsigned short* __restrict__ W2T) {
  int t = blockIdx.x * 256 + threadIdx.x;           // 768*256 = 196608 exact
  if (t < INDIM * HIDDIM) {
    int n = t >> 9, k = t & 511;                    // W1T[n][k] = W1[k][n]
    W1T[t] = f2bf(W1[k * HIDDIM + n]);
  } else {
    int u = t - INDIM * HIDDIM;
    int n = u >> 8, k = u & 255;
    W2T[u] = f2bf(W2[k * HIDDIM + n]);
  }
}

// ---------------- GEMM1: fp32 A fused-convert, pipelined 64x128 tile ----------------
// grid (2, 782); 4 waves as 2Mx2N, wave tile 32x64 (acc[2][4]). K=512, BK=32.
__global__ __launch_bounds__(256) void gemm1_kernel(const float* __restrict__ A,
                                                    const unsigned short* __restrict__ BT,
                                                    const float* __restrict__ dinv,
                                                    unsigned short* __restrict__ Cn) {
  const int M = NODES, K = INDIM;
  constexpr int NK = INDIM / 32;                     // 16
  __shared__ unsigned short As[2][64 * 32];          // 8 KB
  __shared__ unsigned short Bs[2][128 * 32];         // 16 KB
  const int tid = threadIdx.x, wave = tid >> 6, lane = tid & 63;
  const int m0 = blockIdx.y * 64, n0 = blockIdx.x * 128;
  const int wr = wave >> 1, wc = wave & 1;

  f32x4 acc[2][4] = {};
  const int fr = lane & 15, kq = (lane >> 4) * 8;
  const int srow = lane >> 2, scol = (lane & 3) * 8;

  // A-stage mapping: 64x32 fp32 tile = 2048 elems, 2 float4/thread
  const int f0 = tid * 4, f1 = f0 + 1024;
  int ga0 = m0 + (f0 >> 5); if (ga0 > M - 1) ga0 = M - 1;
  int ga1 = m0 + (f1 >> 5); if (ga1 > M - 1) ga1 = M - 1;
  const float* pa0 = A + (size_t)ga0 * K + (f0 & 31);
  const float* pa1 = A + (size_t)ga1 * K + (f1 & 31);

  // B-stage: chunks of 16 rows, wave handles chunk wave*2+c
  const int chunk0 = wave * 2, chunk1 = wave * 2 + 1;
  const unsigned short* pb0 = BT + (size_t)(n0 + chunk0 * 16 + srow) * K + scol;
  const unsigned short* pb1 = BT + (size_t)(n0 + chunk1 * 16 + srow) * K + scol;

  // prologue: stage tile 0 into buf 0
  {
    float4 ra0 = *(const float4*)pa0;
    float4 ra1 = *(const float4*)pa1;
    gload_lds16(pb0, &Bs[0][chunk0 * 512]);
    gload_lds16(pb1, &Bs[0][chunk1 * 512]);
    *(ushort4*)(&As[0][f0]) = cvt4(ra0);
    *(ushort4*)(&As[0][f1]) = cvt4(ra1);
  }
  __syncthreads();

  for (int kt = 0; kt < NK; ++kt) {
    const int cur = kt & 1, nxt = cur ^ 1;
    float4 rb0{}, rb1{};
    if (kt + 1 < NK) {                                // issue next tile early
      const int kc = (kt + 1) * 32;
      rb0 = *(const float4*)(pa0 + kc);
      rb1 = *(const float4*)(pa1 + kc);
      gload_lds16(pb0 + kc, &Bs[nxt][chunk0 * 512]);
      gload_lds16(pb1 + kc, &Bs[nxt][chunk1 * 512]);
    }
    bf16x8 af[2], bq[4];
#pragma unroll
    for (int m = 0; m < 2; ++m) af[m] = *(const bf16x8*)&As[cur][(wr * 32 + m * 16 + fr) * 32 + kq];
#pragma unroll
    for (int n = 0; n < 4; ++n) bq[n] = *(const bf16x8*)&Bs[cur][(wc * 64 + n * 16 + fr) * 32 + kq];
#pragma unroll
    for (int m = 0; m < 2; ++m)
#pragma unroll
      for (int n = 0; n < 4; ++n)
        acc[m][n] = __builtin_amdgcn_mfma_f32_16x16x32_bf16(af[m], bq[n], acc[m][n], 0, 0, 0);
    if (kt + 1 < NK) {                                // land A prefetch into LDS
      *(ushort4*)(&As[nxt][f0]) = cvt4(rb0);
      *(ushort4*)(&As[nxt][f1]) = cvt4(rb1);
    }
    __syncthreads();
  }

  const int rq = (lane >> 4) * 4;
#pragma unroll
  for (int m = 0; m < 2; ++m) {
    int rbase = m0 + wr * 32 + m * 16 + rq;
#pragma unroll
    for (int r = 0; r < 4; ++r) {
      int grow = rbase + r;
      if (grow < M) {
        float dv = dinv[grow];
#pragma unroll
        for (int n = 0; n < 4; ++n) {
          int gcol = n0 + wc * 64 + n * 16 + fr;
          Cn[(size_t)grow * 256 + gcol] = f2bf(acc[m][n][r] * dv);
        }
      }
    }
  }
}

// ---------------- GEMM2: bf16 A, pipelined 64x128 tile, K=256 ----------------
__global__ __launch_bounds__(256) void gemm2_kernel(const unsigned short* __restrict__ A,
                                                    const unsigned short* __restrict__ BT,
                                                    const float* __restrict__ dinv,
                                                    unsigned short* __restrict__ Cn) {
  const int M = NODES, K = HIDDIM;
  constexpr int NK = HIDDIM / 32;                    // 8
  __shared__ unsigned short As[2][64 * 32];
  __shared__ unsigned short Bs[2][128 * 32];
  const int tid = threadIdx.x, wave = tid >> 6, lane = tid & 63;
  const int m0 = blockIdx.y * 64, n0 = blockIdx.x * 128;
  const int wr = wave >> 1, wc = wave & 1;

  f32x4 acc[2][4] = {};
  const int fr = lane & 15, kq = (lane >> 4) * 8;
  const int srow = lane >> 2, scol = (lane & 3) * 8;

  // A: 4 chunks of 16 rows; wave handles chunk=wave
  int gaA = m0 + wave * 16 + srow; if (gaA > M - 1) gaA = M - 1;
  const unsigned short* pa = A + (size_t)gaA * K + scol;
  const int chunk0 = wave * 2, chunk1 = wave * 2 + 1;
  const unsigned short* pb0 = BT + (size_t)(n0 + chunk0 * 16 + srow) * K + scol;
  const unsigned short* pb1 = BT + (size_t)(n0 + chunk1 * 16 + srow) * K + scol;

  gload_lds16(pa, &As[0][wave * 512]);
  gload_lds16(pb0, &Bs[0][chunk0 * 512]);
  gload_lds16(pb1, &Bs[0][chunk1 * 512]);
  __syncthreads();

  for (int kt = 0; kt < NK; ++kt) {
    const int cur = kt & 1, nxt = cur ^ 1;
    if (kt + 1 < NK) {
      const int kc = (kt + 1) * 32;
      gload_lds16(pa + kc, &As[nxt][wave * 512]);
      gload_lds16(pb0 + kc, &Bs[nxt][chunk0 * 512]);
      gload_lds16(pb1 + kc, &Bs[nxt][chunk1 * 512]);
    }
    bf16x8 af[2], bq[4];
#pragma unroll
    for (int m = 0; m < 2; ++m) af[m] = *(const bf16x8*)&As[cur][(wr * 32 + m * 16 + fr) * 32 + kq];
#pragma unroll
    for (int n = 0; n < 4; ++n) bq[n] = *(const bf16x8*)&Bs[cur][(wc * 64 + n * 16 + fr) * 32 + kq];
#pragma unroll
    for (int m = 0; m < 2; ++m)
#pragma unroll
      for (int n = 0; n < 4; ++n)
        acc[m][n] = __builtin_amdgcn_mfma_f32_16x16x32_bf16(af[m], bq[n], acc[m][n], 0, 0, 0);
    __syncthreads();
  }

  const int rq = (lane >> 4) * 4;
#pragma unroll
  for (int m = 0; m < 2; ++m) {
    int rbase = m0 + wr * 32 + m * 16 + rq;
#pragma unroll
    for (int r = 0; r < 4; ++r) {
      int grow = rbase + r;
      if (grow < M) {
        float dv = dinv[grow];
#pragma unroll
        for (int n = 0; n < 4; ++n) {
          int gcol = n0 + wc * 64 + n * 16 + fr;
          Cn[(size_t)grow * 256 + gcol] = f2bf(acc[m][n][r] * dv);
        }
      }
    }
  }
}

// ---------------- gather core: unroll-4 edge loop, 4 rows in flight ----------------
__device__ __forceinline__ float4 gather_node(const unsigned short* __restrict__ hn,
                                              const int* __restrict__ rowptr,
                                              const int* __restrict__ csr,
                                              int node, int c0) {
  ushort4 h = *(const ushort4*)(hn + (size_t)node * 256 + c0);   // self-loop term
  float a0 = bf2f(h.x), a1 = bf2f(h.y), a2 = bf2f(h.z), a3 = bf2f(h.w);
  float b0 = 0.f, b1 = 0.f, b2 = 0.f, b3 = 0.f;
  int e0 = rowptr[node], e1 = rowptr[node + 1];
  int e = e0;
  for (; e + 4 <= e1; e += 4) {
    int s0 = csr[e], s1 = csr[e + 1], s2 = csr[e + 2], s3 = csr[e + 3];
    ushort4 v0 = *(const ushort4*)(hn + (size_t)s0 * 256 + c0);
    ushort4 v1 = *(const ushort4*)(hn + (size_t)s1 * 256 + c0);
    ushort4 v2 = *(const ushort4*)(hn + (size_t)s2 * 256 + c0);
    ushort4 v3 = *(const ushort4*)(hn + (size_t)s3 * 256 + c0);
    a0 += bf2f(v0.x) + bf2f(v1.x);  b0 += bf2f(v2.x) + bf2f(v3.x);
    a1 += bf2f(v0.y) + bf2f(v1.y);  b1 += bf2f(v2.y) + bf2f(v3.y);
    a2 += bf2f(v0.z) + bf2f(v1.z);  b2 += bf2f(v2.z) + bf2f(v3.z);
    a3 += bf2f(v0.w) + bf2f(v1.w);  b3 += bf2f(v2.w) + bf2f(v3.w);
  }
  for (; e < e1; ++e) {
    int s = csr[e];
    ushort4 v = *(const ushort4*)(hn + (size_t)s * 256 + c0);
    a0 += bf2f(v.x); a1 += bf2f(v.y); a2 += bf2f(v.z); a3 += bf2f(v.w);
  }
  return float4{a0 + b0, a1 + b1, a2 + b2, a3 + b3};
}

// ---------------- aggregation: wave per node, CSR gather ----------------
__global__ __launch_bounds__(256) void agg1_kernel(const unsigned short* __restrict__ hn,
                                                   const float* __restrict__ dinv,
                                                   const int* __restrict__ rowptr,
                                                   const int* __restrict__ csr,
                                                   const float* __restrict__ bias,
                                                   unsigned short* __restrict__ outp) {
  int wave = threadIdx.x >> 6, lane = threadIdx.x & 63;
  int node = blockIdx.x * 4 + wave;
  int c0 = lane * 4;
  float4 a = gather_node(hn, rowptr, csr, node, c0);
  float di = dinv[node];
  float4 b = *(const float4*)(bias + c0);
  ushort4 o{f2bf(fmaxf(fmaf(di, a.x, b.x), 0.f)),
            f2bf(fmaxf(fmaf(di, a.y, b.y), 0.f)),
            f2bf(fmaxf(fmaf(di, a.z, b.z), 0.f)),
            f2bf(fmaxf(fmaf(di, a.w, b.w), 0.f))};
  *(ushort4*)(outp + (size_t)node * 256 + c0) = o;
}

__global__ __launch_bounds__(256) void agg2_kernel(const unsigned short* __restrict__ hn,
                                                   const float* __restrict__ dinv,
                                                   const int* __restrict__ rowptr,
                                                   const int* __restrict__ csr,
                                                   const float* __restrict__ bias,
                                                   float* __restrict__ partials) {
  __shared__ float sm[1024];
  int wave = threadIdx.x >> 6, lane = threadIdx.x & 63;
  int node = blockIdx.x * 4 + wave;                 // 12500*4 = 50000 exact
  int c0 = lane * 4;
  float4 a = gather_node(hn, rowptr, csr, node, c0);
  float di = dinv[node];
  float4 b = *(const float4*)(bias + c0);
  sm[wave * 256 + c0 + 0] = fmaxf(fmaf(di, a.x, b.x), 0.f);
  sm[wave * 256 + c0 + 1] = fmaxf(fmaf(di, a.y, b.y), 0.f);
  sm[wave * 256 + c0 + 2] = fmaxf(fmaf(di, a.z, b.z), 0.f);
  sm[wave * 256 + c0 + 3] = fmaxf(fmaf(di, a.w, b.w), 0.f);
  __syncthreads();
  int t = threadIdx.x;
  partials[(size_t)blockIdx.x * 256 + t] = sm[t] + sm[256 + t] + sm[512 + t] + sm[768 + t];
}

// ---------------- readout ----------------
__global__ __launch_bounds__(256) void reduce2_kernel(const float* __restrict__ partials,
                                                      float* __restrict__ p2) {
  int t = threadIdx.x, b = blockIdx.x;              // 64 blocks
  float s = 0.f;
  for (int r = b; r < AGG_BLOCKS; r += RED_BLOCKS) s += partials[(size_t)r * 256 + t];
  p2[b * 256 + t] = s;
}
__global__ __launch_bounds__(256) void final_kernel(const float* __restrict__ p2,
                                                    const float* __restrict__ Wfc,
                                                    const float* __restrict__ bfc,
                                                    float* __restrict__ out) {
  __shared__ float red[256];
  int t = threadIdx.x;
  float s = 0.f;
  for (int b = 0; b < RED_BLOCKS; ++b) s += p2[b * 256 + t];
  float g = s * (1.0f / (float)NODES);
  red[t] = g * Wfc[t];
  __syncthreads();
  for (int off = 128; off > 0; off >>= 1) {
    if (t < off) red[t] += red[t + off];
    __syncthreads();
  }
  if (t == 0) {
    float z = red[0] + bfc[0];
    out[0] = 1.0f / (1.0f + expf(-z));
  }
}

// ---------------- launch ----------------
extern "C" void kernel_launch(void* const* d_in, const int* in_sizes, int n_in,
                              void* d_out, int out_size, void* d_ws, size_t ws_size,
                              hipStream_t stream) {
  (void)in_sizes; (void)n_in; (void)out_size; (void)ws_size;
  const float* x   = (const float*)d_in[0];
  const int*   ei  = (const int*)d_in[1];
  const float* W1  = (const float*)d_in[2];
  const float* b1  = (const float*)d_in[3];
  const float* W2  = (const float*)d_in[4];
  const float* b2  = (const float*)d_in[5];
  const float* Wfc = (const float*)d_in[6];
  const float* bfc = (const float*)d_in[7];
  float* out = (float*)d_out;
  char* ws = (char*)d_ws;

  unsigned short* hn   = (unsigned short*)(ws + OFF_HN);
  unsigned short* h1p  = (unsigned short*)(ws + OFF_H1P);
  unsigned short* w1t  = (unsigned short*)(ws + OFF_W1T);
  unsigned short* w2t  = (unsigned short*)(ws + OFF_W2T);
  int*   deg    = (int*)(ws + OFF_DEG);
  int*   fill   = (int*)(ws + OFF_FILL);
  int*   rowptr = (int*)(ws + OFF_ROWP);
  int*   csr    = (int*)(ws + OFF_CSR);
  int*   bsum   = (int*)(ws + OFF_BSUM);
  int*   boff   = (int*)(ws + OFF_BOFF);
  int*   flag   = (int*)(ws + OFF_FLAG);
  float* part   = (float*)(ws + OFF_PART);
  float* p2     = (float*)(ws + OFF_P2);
  float* dinv   = (float*)(ws + OFF_DINV);

  hipMemsetAsync(ws + OFF_DEG, 0, 400000, stream);  // deg + fill
  detect_kernel<<<1, 64, 0, stream>>>(ei, flag);
  hist_kernel<<<EDGES / 256, 256, 0, stream>>>(ei, flag, deg);
  scan1_kernel<<<NB_SCAN, 256, 0, stream>>>(deg, rowptr, bsum, dinv);
  scan2_kernel<<<1, 256, 0, stream>>>(bsum, boff, rowptr + NODES);
  scan3_kernel<<<NB_SCAN, 256, 0, stream>>>(rowptr, boff);
  fill_kernel<<<EDGES / 256, 256, 0, stream>>>(ei, flag, rowptr, fill, csr);

  transw_kernel<<<(INDIM * HIDDIM + HIDDIM * HIDDIM) / 256, 256, 0, stream>>>(W1, W2, w1t, w2t);

  dim3 ggrid(HIDDIM / 128, GEMM_MB);                // (2, 782)
  gemm1_kernel<<<ggrid, 256, 0, stream>>>(x, w1t, dinv, hn);
  agg1_kernel<<<AGG_BLOCKS, 256, 0, stream>>>(hn, dinv, rowptr, csr, b1, h1p);
  gemm2_kernel<<<ggrid, 256, 0, stream>>>(h1p, w2t, dinv, hn);
  agg2_kernel<<<AGG_BLOCKS, 256, 0, stream>>>(hn, dinv, rowptr, csr, b2, part);
  reduce2_kernel<<<RED_BLOCKS, 256, 0, stream>>>(part, p2);
  final_kernel<<<1, 256, 0, stream>>>(p2, Wfc, bfc, out);
}